// Round 3
// baseline (1795.846 us; speedup 1.0000x reference)
//
#include <hip/hip_runtime.h>

#define N_FEAT 64
#define NBINS 256
#define HIST_FLOATS (N_FEAT * NBINS)   // 16384 floats per histogram
#define BLOCK_A 512
#define GRID_A 256
#define UNROLL 8

// Kernel A: per-block privatized histogram in LDS (64 feat x 256 bins x {g,h}
// = 128 KiB), lane i owns feature i. One coalesced 256B row load per wave.
__global__ __launch_bounds__(BLOCK_A) void _split_hist_kernel(
    const int* __restrict__ X, const float* __restrict__ grad,
    const float* __restrict__ hess, float* __restrict__ ws, int n)
{
    __shared__ float hg[HIST_FLOATS];
    __shared__ float hh[HIST_FLOATS];
    for (int i = threadIdx.x; i < HIST_FLOATS; i += BLOCK_A) {
        hg[i] = 0.f;
        hh[i] = 0.f;
    }
    __syncthreads();

    const int lane = threadIdx.x & 63;
    const int wid  = (int)((blockIdx.x * BLOCK_A + threadIdx.x) >> 6);
    const int nw   = (GRID_A * BLOCK_A) >> 6;   // total waves = 2048

    float* hgl = &hg[lane * NBINS];
    float* hhl = &hh[lane * NBINS];

    for (int r0 = wid * UNROLL; r0 < n; r0 += nw * UNROLL) {
        const int ru = __builtin_amdgcn_readfirstlane(r0);

        int   bins[UNROLL];
        float gv[UNROLL];
        float hv[UNROLL];
        #pragma unroll
        for (int j = 0; j < UNROLL; ++j) {
            const int r = ru + j;
            if (r < n) {
                bins[j] = X[(size_t)r * N_FEAT + lane];
                gv[j]   = grad[r];
                hv[j]   = hess[r];
            } else {
                bins[j] = 0;
                gv[j]   = 0.f;
                hv[j]   = 0.f;
            }
        }
        #pragma unroll
        for (int j = 0; j < UNROLL; ++j) {
            unsafeAtomicAdd(&hgl[bins[j]], gv[j]);   // ds_add_f32
            unsafeAtomicAdd(&hhl[bins[j]], hv[j]);
        }
    }
    __syncthreads();

    // Flush block-private histograms into the global accumulator in ws.
    for (int i = threadIdx.x; i < HIST_FLOATS; i += BLOCK_A) {
        unsafeAtomicAdd(&ws[i], hg[i]);                     // global_atomic_add_f32
        unsafeAtomicAdd(&ws[HIST_FLOATS + i], hh[i]);
    }
}

// Kernel B: inclusive scan over 256 bins for each of 128 rows
// (rows 0..63 = gradient features, 64..127 = hessian features).
__global__ __launch_bounds__(NBINS) void _split_scan_kernel(
    const float* __restrict__ ws, float* __restrict__ out)
{
    __shared__ float s[NBINS];
    const int row = blockIdx.x;
    const int t   = threadIdx.x;

    s[t] = ws[row * NBINS + t];
    __syncthreads();

    #pragma unroll
    for (int off = 1; off < NBINS; off <<= 1) {
        float x = (t >= off) ? s[t - off] : 0.f;
        __syncthreads();
        s[t] += x;
        __syncthreads();
    }
    out[row * NBINS + t] = s[t];
}

extern "C" void kernel_launch(void* const* d_in, const int* in_sizes, int n_in,
                              void* d_out, int out_size, void* d_ws, size_t ws_size,
                              hipStream_t stream) {
    const int*   X    = (const int*)d_in[0];
    const float* grad = (const float*)d_in[1];
    const float* hess = (const float*)d_in[2];
    float*       out  = (float*)d_out;
    float*       ws   = (float*)d_ws;
    const int n = in_sizes[1];   // N_SAMPLES (gradient element count)

    hipMemsetAsync(d_ws, 0, 2 * HIST_FLOATS * sizeof(float), stream);
    hipLaunchKernelGGL(_split_hist_kernel, dim3(GRID_A), dim3(BLOCK_A), 0, stream,
                       X, grad, hess, ws, n);
    hipLaunchKernelGGL(_split_scan_kernel, dim3(2 * N_FEAT), dim3(NBINS), 0, stream,
                       ws, out);
}

// Round 5
// 1784.044 us; speedup vs baseline: 1.0066x; 1.0066x over previous
//
#include <hip/hip_runtime.h>

#define N_FEAT 64
#define NBINS 256
#define FQ 16                                  // features per block (quarter)
#define QHIST (FQ * NBINS)                     // 4096 floats per block histogram
#define HIST_FLOATS (N_FEAT * NBINS)           // 16384 floats per full histogram
#define BLOCK_A 512
#define NQ 4                                   // feature quarters
#define BLKS_PER_Q 256
#define GRID_A (NQ * BLKS_PER_Q)               // 1024 blocks
#define WAVES_PER_Q (BLKS_PER_Q * (BLOCK_A / 64))   // 2048 waves per quarter
#define ROWS_PER_WAVE 16

// Kernel A: feature-quartered privatized histograms. Each block owns 16
// features (32 KiB LDS -> 4 blocks/CU, 32 waves/CU). Lane l of a wave loads
// int4 = 4 features of row r0+(l>>2); 16 rows per load instruction as 16
// exact 64B cache lines. LDS accumulation via explicit ds_add_f32 inline asm
// (low 32 bits of an LDS flat pointer are the LDS byte offset on gfx9+),
// avoiding the flat_atomic_add lowering that serialized round 3.
__global__ __launch_bounds__(BLOCK_A, 8) void _split_hist_kernel(
    const int* __restrict__ X, const float* __restrict__ grad,
    const float* __restrict__ hess, float* __restrict__ ws, int n)
{
    __shared__ float hg[QHIST];
    __shared__ float hh[QHIST];
    for (int i = threadIdx.x; i < QHIST; i += BLOCK_A) {
        hg[i] = 0.f;
        hh[i] = 0.f;
    }
    __syncthreads();

    const int q    = blockIdx.x & (NQ - 1);
    const int lane = threadIdx.x & 63;
    const int wq   = ((blockIdx.x >> 2) << 3) + (threadIdx.x >> 6); // 0..2047
    const int fg   = lane & 3;    // 4-feature group within the quarter
    const int rsub = lane >> 2;   // row offset 0..15

    // LDS byte addresses of this lane's 4 feature rows (g and h).
    const unsigned bg = (unsigned)(size_t)&hg[fg * 4 * NBINS];
    const unsigned bh = (unsigned)(size_t)&hh[fg * 4 * NBINS];

    const int fcol = q * FQ + fg * 4;   // global feature column of b4.x

    for (int r0 = wq * ROWS_PER_WAVE; r0 < n; r0 += WAVES_PER_Q * ROWS_PER_WAVE) {
        const int row = r0 + rsub;
        const int rc  = row < n ? row : n - 1;
        const int4 b4 = *reinterpret_cast<const int4*>(&X[(size_t)rc * N_FEAT + fcol]);
        float g = grad[rc];
        float h = hess[rc];
        if (row >= n) { g = 0.f; h = 0.f; }   // add 0.0 -> harmless

        asm volatile("ds_add_f32 %0, %1" :: "v"(bg +          ((unsigned)b4.x << 2)), "v"(g));
        asm volatile("ds_add_f32 %0, %1" :: "v"(bg + 1024u + ((unsigned)b4.y << 2)), "v"(g));
        asm volatile("ds_add_f32 %0, %1" :: "v"(bg + 2048u + ((unsigned)b4.z << 2)), "v"(g));
        asm volatile("ds_add_f32 %0, %1" :: "v"(bg + 3072u + ((unsigned)b4.w << 2)), "v"(g));
        asm volatile("ds_add_f32 %0, %1" :: "v"(bh +          ((unsigned)b4.x << 2)), "v"(h));
        asm volatile("ds_add_f32 %0, %1" :: "v"(bh + 1024u + ((unsigned)b4.y << 2)), "v"(h));
        asm volatile("ds_add_f32 %0, %1" :: "v"(bh + 2048u + ((unsigned)b4.z << 2)), "v"(h));
        asm volatile("ds_add_f32 %0, %1" :: "v"(bh + 3072u + ((unsigned)b4.w << 2)), "v"(h));
    }

    // Drain our untracked (inline-asm) DS ops before the barrier, then flush.
    asm volatile("s_waitcnt lgkmcnt(0)" ::: "memory");
    __syncthreads();

    const int base = q * FQ * NBINS;
    for (int i = threadIdx.x; i < QHIST; i += BLOCK_A) {
        unsafeAtomicAdd(&ws[base + i], hg[i]);                       // global_atomic_add_f32
        unsafeAtomicAdd(&ws[HIST_FLOATS + base + i], hh[i]);
    }
}

// Kernel B: inclusive scan over 256 bins for each of 128 rows
// (rows 0..63 = gradient features, 64..127 = hessian features).
__global__ __launch_bounds__(NBINS) void _split_scan_kernel(
    const float* __restrict__ ws, float* __restrict__ out)
{
    __shared__ float s[NBINS];
    const int row = blockIdx.x;
    const int t   = threadIdx.x;

    s[t] = ws[row * NBINS + t];
    __syncthreads();

    #pragma unroll
    for (int off = 1; off < NBINS; off <<= 1) {
        float x = (t >= off) ? s[t - off] : 0.f;
        __syncthreads();
        s[t] += x;
        __syncthreads();
    }
    out[row * NBINS + t] = s[t];
}

extern "C" void kernel_launch(void* const* d_in, const int* in_sizes, int n_in,
                              void* d_out, int out_size, void* d_ws, size_t ws_size,
                              hipStream_t stream) {
    const int*   X    = (const int*)d_in[0];
    const float* grad = (const float*)d_in[1];
    const float* hess = (const float*)d_in[2];
    float*       out  = (float*)d_out;
    float*       ws   = (float*)d_ws;
    const int n = in_sizes[1];   // N_SAMPLES (gradient element count)

    hipMemsetAsync(d_ws, 0, 2 * HIST_FLOATS * sizeof(float), stream);
    hipLaunchKernelGGL(_split_hist_kernel, dim3(GRID_A), dim3(BLOCK_A), 0, stream,
                       X, grad, hess, ws, n);
    hipLaunchKernelGGL(_split_scan_kernel, dim3(2 * N_FEAT), dim3(NBINS), 0, stream,
                       ws, out);
}

// Round 6
// 1348.095 us; speedup vs baseline: 1.3321x; 1.3234x over previous
//
#include <hip/hip_runtime.h>

#define N_FEAT 64
#define NBINS 256
#define NB2 260                      // +4 pad: bins 256..259 are per-lane dummy slots
#define HIST_FLOATS (N_FEAT * NBINS) // 16384 per histogram (g or h)
#define NBLOCKS 256                  // 1 block per CU (LDS-capped)
#define BLOCK_T 128                  // 2 waves
#define CHUNK 32                     // rows per pipeline iteration
#define PARTIAL_FLOATS 32768         // per-block flush size (2*16384)
#define WS_PARTIAL_BYTES ((size_t)NBLOCKS * PARTIAL_FLOATS * sizeof(float))

// Kernel A: atomic-free histogram. Wave w owns features [32w,32w+32).
// Lane f (<32): g-histogram of feature 32w+f; lane f+32: h-histogram of the
// same feature. Each lane's 260-float LDS region is exclusively owned ->
// plain ds_read/add/ds_write RMW (no atomics; LDS f32 atomics measured
// lane-serialized at ~3.1 cyc/lane in rounds 3+5 = 1.25 ms floor).
// Rows are processed in quads: bins deduped in registers, duplicate rows
// redirected to the lane's dummy slot, so the 4 in-flight RMWs never alias
// (same-wave DS ops process in order, guaranteeing cross-quad correctness).
__global__ __launch_bounds__(BLOCK_T, 1) void _split_hist_kernel(
    const int* __restrict__ X, const float* __restrict__ grad,
    const float* __restrict__ hess, float* __restrict__ ws, int n, int mode)
{
    __shared__ float hist[2][N_FEAT][NB2];   // 133,120 B
    const int tid  = threadIdx.x;
    const int w    = tid >> 6;               // wave 0/1
    const int lane = tid & 63;

    for (int i = tid; i < 2 * N_FEAT * NB2; i += BLOCK_T)
        (&hist[0][0][0])[i] = 0.f;
    __syncthreads();

    const int  col = w * 32 + (lane & 31);   // feature column this lane reads
    const bool isG = lane < 32;

    const int R    = (n + NBLOCKS - 1) / NBLOCKS;
    const int rbeg = blockIdx.x * R;
    const int rend = min(rbeg + R, n);

    for (int c = rbeg; c < rend; c += CHUNK) {
        int bins[CHUNK];
        #pragma unroll
        for (int j = 0; j < CHUNK; ++j) {
            int r = c + j;
            r = r < rend ? r : rend - 1;     // clamped dups dedupe to 0-adds
            bins[j] = X[(size_t)r * N_FEAT + col];
        }
        #pragma unroll
        for (int q = 0; q < CHUNK / 4; ++q) {
            float v[4];
            int   b[4];
            #pragma unroll
            for (int j = 0; j < 4; ++j) {
                const int  r  = c + q * 4 + j;
                const bool ok = r < rend;
                const int  rc = ok ? r : rend - 1;
                const float gv = grad[rc];
                const float hv = hess[rc];
                v[j] = ok ? (isG ? gv : hv) : 0.f;
                b[j] = bins[q * 4 + j];
            }
            // Dedupe: route later rows' values into the first equal bin.
            const bool e10 = b[1] == b[0];
            const bool e20 = b[2] == b[0], e21 = b[2] == b[1];
            const bool e30 = b[3] == b[0], e31 = b[3] == b[1], e32 = b[3] == b[2];
            const float v0 = v[0] + (e10 ? v[1] : 0.f) + (e20 ? v[2] : 0.f) + (e30 ? v[3] : 0.f);
            const float v1 = v[1] + ((!e20 && e21) ? v[2] : 0.f) + ((!e30 && e31) ? v[3] : 0.f);
            const float v2 = v[2] + ((!e30 && !e31 && e32) ? v[3] : 0.f);
            const float v3 = v[3];
            const int a0 = b[0];
            const int a1 = e10                ? 256 : b[1];   // 256.. = dummy slots
            const int a2 = (e20 || e21)       ? 257 : b[2];
            const int a3 = (e30 || e31 || e32) ? 258 : b[3];
            // 4 parallel RMWs to distinct addresses within the lane's region.
            const float t0 = hist[w][lane][a0];
            const float t1 = hist[w][lane][a1];
            const float t2 = hist[w][lane][a2];
            const float t3 = hist[w][lane][a3];
            hist[w][lane][a0] = t0 + v0;
            hist[w][lane][a1] = t1 + v1;
            hist[w][lane][a2] = t2 + v2;
            hist[w][lane][a3] = t3 + v3;
        }
    }
    __syncthreads();

    // Flush. mode=1: non-atomic per-block partials ws[block][wv][reg][bin];
    // mode=0: f32 global atomics into ws[type][feat][bin] (ws pre-zeroed).
    if (mode) {
        float* dst = ws + (size_t)blockIdx.x * PARTIAL_FLOATS;
        for (int i = tid; i < PARTIAL_FLOATS; i += BLOCK_T) {
            const int wv  = i >> 14;
            const int reg = (i >> 8) & 63;
            const int bin = i & 255;
            dst[i] = hist[wv][reg][bin];
        }
    } else {
        for (int i = tid; i < PARTIAL_FLOATS; i += BLOCK_T) {
            const int wv   = i >> 14;
            const int reg  = (i >> 8) & 63;
            const int bin  = i & 255;
            const int type = reg >> 5;
            const int feat = wv * 32 + (reg & 31);
            unsafeAtomicAdd(&ws[type * HIST_FLOATS + feat * NBINS + bin],
                            hist[wv][reg][bin]);
        }
    }
}

// Kernel B: reduce partials (mode=1) + inclusive scan over 256 bins for each
// of 128 rows (rows 0..63 = gradient features, 64..127 = hessian features).
__global__ __launch_bounds__(NBINS) void _split_scan_kernel(
    const float* __restrict__ ws, float* __restrict__ out, int mode)
{
    __shared__ float s[NBINS];
    const int row = blockIdx.x;
    const int t   = threadIdx.x;

    float acc;
    if (mode) {
        const int type = row >> 6;
        const int feat = row & 63;
        const int wv   = feat >> 5;
        const int reg  = (type << 5) | (feat & 31);
        const size_t slot = ((size_t)wv << 14) | (reg << 8) | t;
        acc = 0.f;
        for (int p = 0; p < NBLOCKS; ++p)
            acc += ws[(size_t)p * PARTIAL_FLOATS + slot];
    } else {
        acc = ws[row * NBINS + t];
    }
    s[t] = acc;
    __syncthreads();

    #pragma unroll
    for (int off = 1; off < NBINS; off <<= 1) {
        float x = (t >= off) ? s[t - off] : 0.f;
        __syncthreads();
        s[t] += x;
        __syncthreads();
    }
    out[row * NBINS + t] = s[t];
}

extern "C" void kernel_launch(void* const* d_in, const int* in_sizes, int n_in,
                              void* d_out, int out_size, void* d_ws, size_t ws_size,
                              hipStream_t stream) {
    const int*   X    = (const int*)d_in[0];
    const float* grad = (const float*)d_in[1];
    const float* hess = (const float*)d_in[2];
    float*       out  = (float*)d_out;
    float*       ws   = (float*)d_ws;
    const int n = in_sizes[1];   // N_SAMPLES

    const int mode = (ws_size >= WS_PARTIAL_BYTES) ? 1 : 0;
    if (!mode)
        hipMemsetAsync(d_ws, 0, 2 * HIST_FLOATS * sizeof(float), stream);

    hipLaunchKernelGGL(_split_hist_kernel, dim3(NBLOCKS), dim3(BLOCK_T), 0, stream,
                       X, grad, hess, ws, n, mode);
    hipLaunchKernelGGL(_split_scan_kernel, dim3(2 * N_FEAT), dim3(NBINS), 0, stream,
                       ws, out, mode);
}

// Round 7
// 1147.546 us; speedup vs baseline: 1.5649x; 1.1748x over previous
//
#include <hip/hip_runtime.h>

#define N_FEAT 64
#define NBINS 256
#define NB2 260                      // +4 pad: bins 256..259 are per-lane dummy slots
#define HIST_FLOATS (N_FEAT * NBINS) // 16384 per histogram (g or h)
#define NBLOCKS 256                  // 1 block per CU (LDS-capped)
#define BLOCK_T 128                  // 2 waves
#define CHUNK 32                     // rows per pipeline stage
#define PARTIAL_FLOATS 32768         // per-block flush size (2*16384)
#define WS_PARTIAL_BYTES ((size_t)NBLOCKS * PARTIAL_FLOATS * sizeof(float))

// Load one chunk: 32 bin columns (coalesced 128B/row) + this lane's val
// (lane<32 -> grad[c+lane], lane>=32 -> hess[c+lane-32]; one vector load).
__device__ __forceinline__ void load_chunk(const int* __restrict__ X,
    const float* __restrict__ grad, const float* __restrict__ hess,
    int c, int rend, int col, int lane, int (&bins)[CHUNK], float& val)
{
    #pragma unroll
    for (int j = 0; j < CHUNK; ++j) {
        int r = c + j; r = r < rend ? r : rend - 1;   // clamped dups add 0
        bins[j] = X[(size_t)r * N_FEAT + col];
    }
    int rv = c + (lane & 31); rv = rv < rend ? rv : rend - 1;
    val = (lane < 32) ? grad[rv] : hess[rv];
}

// Exclusive-ownership RMW with quad dedup (round-6 verified logic). Row r's
// val reaches every lane via __shfl from the lane that loaded it.
__device__ __forceinline__ void process_chunk(float (&hist)[2][N_FEAT][NB2],
    int w, int lane, int c, int rend, const int (&bins)[CHUNK], float val)
{
    #pragma unroll
    for (int q = 0; q < CHUNK / 4; ++q) {
        float v[4]; int b[4];
        #pragma unroll
        for (int j = 0; j < 4; ++j) {
            const int r = c + q * 4 + j;
            const float vv = __shfl(val, (lane & 32) + q * 4 + j);
            v[j] = (r < rend) ? vv : 0.f;
            b[j] = bins[q * 4 + j];
        }
        const bool e10 = b[1] == b[0];
        const bool e20 = b[2] == b[0], e21 = b[2] == b[1];
        const bool e30 = b[3] == b[0], e31 = b[3] == b[1], e32 = b[3] == b[2];
        const float v0 = v[0] + (e10 ? v[1] : 0.f) + (e20 ? v[2] : 0.f) + (e30 ? v[3] : 0.f);
        const float v1 = v[1] + ((!e20 && e21) ? v[2] : 0.f) + ((!e30 && e31) ? v[3] : 0.f);
        const float v2 = v[2] + ((!e30 && !e31 && e32) ? v[3] : 0.f);
        const float v3 = v[3];
        const int a0 = b[0];
        const int a1 = e10                 ? 256 : b[1];
        const int a2 = (e20 || e21)        ? 257 : b[2];
        const int a3 = (e30 || e31 || e32) ? 258 : b[3];
        const float t0 = hist[w][lane][a0];
        const float t1 = hist[w][lane][a1];
        const float t2 = hist[w][lane][a2];
        const float t3 = hist[w][lane][a3];
        hist[w][lane][a0] = t0 + v0;
        hist[w][lane][a1] = t1 + v1;
        hist[w][lane][a2] = t2 + v2;
        hist[w][lane][a3] = t3 + v3;
    }
}

// Kernel A: atomic-free histogram, register-double-buffered. Wave w owns
// features [32w,32w+32): lane f<32 = g-hist, lane f+32 = h-hist of feat 32w+f.
__global__ __launch_bounds__(BLOCK_T, 1) void _split_hist_kernel(
    const int* __restrict__ X, const float* __restrict__ grad,
    const float* __restrict__ hess, float* __restrict__ ws, int n, int mode)
{
    __shared__ float hist[2][N_FEAT][NB2];   // 133,120 B
    const int tid  = threadIdx.x;
    const int w    = tid >> 6;
    const int lane = tid & 63;

    for (int i = tid; i < 2 * N_FEAT * NB2; i += BLOCK_T)
        (&hist[0][0][0])[i] = 0.f;
    __syncthreads();

    const int col  = w * 32 + (lane & 31);
    const int R    = (n + NBLOCKS - 1) / NBLOCKS;
    const int rbeg = blockIdx.x * R;
    const int rend = min(rbeg + R, n);

    if (rbeg < rend) {
        int   binsA[CHUNK], binsB[CHUNK];
        float valA, valB;
        load_chunk(X, grad, hess, rbeg, rend, col, lane, binsA, valA);
        for (int c = rbeg; c < rend; c += 2 * CHUNK) {
            const int c1 = c + CHUNK, c2 = c + 2 * CHUNK;
            if (c1 < rend)
                load_chunk(X, grad, hess, c1, rend, col, lane, binsB, valB);
            process_chunk(hist, w, lane, c, rend, binsA, valA);
            if (c1 < rend) {
                if (c2 < rend)
                    load_chunk(X, grad, hess, c2, rend, col, lane, binsA, valA);
                process_chunk(hist, w, lane, c1, rend, binsB, valB);
            }
        }
    }
    __syncthreads();

    // Flush. mode=1: non-atomic per-block partials ws[block][wv][reg][bin];
    // mode=0: f32 global atomics into ws[type][feat][bin] (ws pre-zeroed).
    if (mode) {
        float* dst = ws + (size_t)blockIdx.x * PARTIAL_FLOATS;
        for (int i = tid; i < PARTIAL_FLOATS; i += BLOCK_T) {
            const int wv  = i >> 14;
            const int reg = (i >> 8) & 63;
            const int bin = i & 255;
            dst[i] = hist[wv][reg][bin];
        }
    } else {
        for (int i = tid; i < PARTIAL_FLOATS; i += BLOCK_T) {
            const int wv   = i >> 14;
            const int reg  = (i >> 8) & 63;
            const int bin  = i & 255;
            const int type = reg >> 5;
            const int feat = wv * 32 + (reg & 31);
            unsafeAtomicAdd(&ws[type * HIST_FLOATS + feat * NBINS + bin],
                            hist[wv][reg][bin]);
        }
    }
}

// Kernel B: reduce partials (mode=1) + inclusive scan over 256 bins for each
// of 128 rows (rows 0..63 = gradient features, 64..127 = hessian features).
__global__ __launch_bounds__(NBINS) void _split_scan_kernel(
    const float* __restrict__ ws, float* __restrict__ out, int mode)
{
    __shared__ float s[NBINS];
    const int row = blockIdx.x;
    const int t   = threadIdx.x;

    float acc;
    if (mode) {
        const int type = row >> 6;
        const int feat = row & 63;
        const int wv   = feat >> 5;
        const int reg  = (type << 5) | (feat & 31);
        const size_t slot = ((size_t)wv << 14) | (reg << 8) | t;
        acc = 0.f;
        for (int p = 0; p < NBLOCKS; ++p)
            acc += ws[(size_t)p * PARTIAL_FLOATS + slot];
    } else {
        acc = ws[row * NBINS + t];
    }
    s[t] = acc;
    __syncthreads();

    #pragma unroll
    for (int off = 1; off < NBINS; off <<= 1) {
        float x = (t >= off) ? s[t - off] : 0.f;
        __syncthreads();
        s[t] += x;
        __syncthreads();
    }
    out[row * NBINS + t] = s[t];
}

extern "C" void kernel_launch(void* const* d_in, const int* in_sizes, int n_in,
                              void* d_out, int out_size, void* d_ws, size_t ws_size,
                              hipStream_t stream) {
    const int*   X    = (const int*)d_in[0];
    const float* grad = (const float*)d_in[1];
    const float* hess = (const float*)d_in[2];
    float*       out  = (float*)d_out;
    float*       ws   = (float*)d_ws;
    const int n = in_sizes[1];   // N_SAMPLES

    const int mode = (ws_size >= WS_PARTIAL_BYTES) ? 1 : 0;
    if (!mode)
        hipMemsetAsync(d_ws, 0, 2 * HIST_FLOATS * sizeof(float), stream);

    hipLaunchKernelGGL(_split_hist_kernel, dim3(NBLOCKS), dim3(BLOCK_T), 0, stream,
                       X, grad, hess, ws, n, mode);
    hipLaunchKernelGGL(_split_scan_kernel, dim3(2 * N_FEAT), dim3(NBINS), 0, stream,
                       ws, out, mode);
}

// Round 8
// 942.890 us; speedup vs baseline: 1.9046x; 1.2171x over previous
//
#include <hip/hip_runtime.h>

#define N_FEAT 64
#define NBINS 256
#define NB2 260                       // 256 bins + 3 dummy slots + pad
#define HIST_FLOATS (N_FEAT * NBINS)  // 16384 per histogram type
#define NBLOCKS 256                   // 1 block per CU (LDS-capped)
#define BLOCK_T 128                   // 2 waves: wave0 = grad, wave1 = hess
#define CHUNK 32                      // rows per pipeline stage
#define PARTIAL_FLOATS (2 * HIST_FLOATS)   // 32768 per-block flush
#define WS_PARTIAL_BYTES ((size_t)NBLOCKS * PARTIAL_FLOATS * sizeof(float))

// Bins for rows [c, c+32): lane = feature column -> 256B coalesced row loads.
__device__ __forceinline__ void load_bins(const int* __restrict__ Xl,
    int c, int rend, int (&bins)[CHUNK])
{
    if (c + CHUNK <= rend) {
        #pragma unroll
        for (int j = 0; j < CHUNK; ++j)
            bins[j] = Xl[(size_t)(c + j) * N_FEAT];
    } else {
        #pragma unroll
        for (int j = 0; j < CHUNK; ++j) {
            int r = c + j; r = r < rend ? r : rend - 1;  // dup rows get val 0
            bins[j] = Xl[(size_t)r * N_FEAT];
        }
    }
}

// Values for rows [c, c+32): wave-uniform address -> scalar (SGPR) loads.
__device__ __forceinline__ void load_vals(const float* __restrict__ vp,
    int c, int rend, float (&val)[CHUNK])
{
    if (c + CHUNK <= rend) {
        #pragma unroll
        for (int j = 0; j < CHUNK / 4; ++j) {
            const float4 v4 = *reinterpret_cast<const float4*>(vp + c + 4 * j);
            val[4*j+0] = v4.x; val[4*j+1] = v4.y; val[4*j+2] = v4.z; val[4*j+3] = v4.w;
        }
    } else {
        #pragma unroll
        for (int j = 0; j < CHUNK; ++j)
            val[j] = (c + j < rend) ? vp[c + j] : 0.f;
    }
}

// Exclusive-ownership RMW with quad dedup (round-6/7 verified logic).
// hrow = this lane's 260-float private histogram row. Same-wave DS ops are
// processed in order, so cross-quad RAW needs no explicit wait.
__device__ __forceinline__ void process_chunk(float* __restrict__ hrow,
    const int (&bins)[CHUNK], const float (&val)[CHUNK])
{
    #pragma unroll
    for (int q = 0; q < CHUNK / 4; ++q) {
        const int   b0 = bins[4*q+0], b1 = bins[4*q+1], b2 = bins[4*q+2], b3 = bins[4*q+3];
        const float v0 = val[4*q+0], v1 = val[4*q+1], v2 = val[4*q+2], v3 = val[4*q+3];
        const bool e10 = b1 == b0;
        const bool e20 = b2 == b0, e21 = b2 == b1;
        const bool e30 = b3 == b0, e31 = b3 == b1, e32 = b3 == b2;
        const float s0 = v0 + (e10 ? v1 : 0.f) + (e20 ? v2 : 0.f) + (e30 ? v3 : 0.f);
        const float s1 = v1 + ((!e20 && e21) ? v2 : 0.f) + ((!e30 && e31) ? v3 : 0.f);
        const float s2 = v2 + ((!e30 && !e31 && e32) ? v3 : 0.f);
        const float s3 = v3;
        const int a0 = b0;
        const int a1 = e10                 ? 256 : b1;   // 256..258 = dummies
        const int a2 = (e20 || e21)        ? 257 : b2;
        const int a3 = (e30 || e31 || e32) ? 258 : b3;
        const float t0 = hrow[a0], t1 = hrow[a1], t2 = hrow[a2], t3 = hrow[a3];
        hrow[a0] = t0 + s0;
        hrow[a1] = t1 + s1;
        hrow[a2] = t2 + s2;
        hrow[a3] = t3 + s3;
    }
}

// Kernel A: atomic-free histogram. Wave 0: lane f owns grad-hist of feature
// f; wave 1: hess-hist. Add-values are wave-uniform (SGPR), X row loads are
// fully coalesced 256B, and the only DS traffic is the irreducible RMW.
__global__ __launch_bounds__(BLOCK_T, 1) void _split_hist_kernel(
    const int* __restrict__ X, const float* __restrict__ grad,
    const float* __restrict__ hess, float* __restrict__ ws, int n, int mode)
{
    __shared__ float hist[2][N_FEAT][NB2];   // 133,120 B
    const int tid  = threadIdx.x;
    const int w    = tid >> 6;               // 0 = grad, 1 = hess
    const int lane = tid & 63;               // feature

    for (int i = tid; i < 2 * N_FEAT * NB2; i += BLOCK_T)
        (&hist[0][0][0])[i] = 0.f;
    __syncthreads();

    const float* vp   = w ? hess : grad;     // wave-uniform select
    const int*   Xl   = X + lane;
    float*       hrow = &hist[w][lane][0];

    const int R    = (((n + NBLOCKS - 1) / NBLOCKS) + CHUNK - 1) / CHUNK * CHUNK;
    const int rbeg = blockIdx.x * R;
    const int rend = min(rbeg + R, n);

    if (rbeg < rend) {
        int   binsA[CHUNK], binsB[CHUNK];
        float valA[CHUNK], valB[CHUNK];
        load_bins(Xl, rbeg, rend, binsA);
        load_vals(vp, rbeg, rend, valA);
        for (int c = rbeg; c < rend; c += 2 * CHUNK) {
            const int c1 = c + CHUNK, c2 = c + 2 * CHUNK;
            if (c1 < rend) {
                load_bins(Xl, c1, rend, binsB);
                load_vals(vp, c1, rend, valB);
            }
            process_chunk(hrow, binsA, valA);
            if (c1 < rend) {
                if (c2 < rend) {
                    load_bins(Xl, c2, rend, binsA);
                    load_vals(vp, c2, rend, valA);
                }
                process_chunk(hrow, binsB, valB);
            }
        }
    }
    __syncthreads();

    // Flush (pad-stripped). mode=1: per-block partials ws[block][type][feat][bin];
    // mode=0: f32 global atomics into ws[type][feat][bin] (ws pre-zeroed).
    if (mode) {
        float* dst = ws + (size_t)blockIdx.x * PARTIAL_FLOATS;
        for (int i = tid; i < PARTIAL_FLOATS; i += BLOCK_T) {
            const int ty  = i >> 14;
            const int fe  = (i >> 8) & 63;
            const int bin = i & 255;
            dst[i] = hist[ty][fe][bin];
        }
    } else {
        for (int i = tid; i < PARTIAL_FLOATS; i += BLOCK_T) {
            const int ty  = i >> 14;
            const int fe  = (i >> 8) & 63;
            const int bin = i & 255;
            unsafeAtomicAdd(&ws[i], hist[ty][fe][bin]);
        }
    }
}

// Kernel B: reduce partials (mode=1) + inclusive scan over 256 bins for each
// of 128 rows (row = type*64 + feature; 0..63 grad, 64..127 hess).
__global__ __launch_bounds__(NBINS) void _split_scan_kernel(
    const float* __restrict__ ws, float* __restrict__ out, int mode)
{
    __shared__ float s[NBINS];
    const int row = blockIdx.x;
    const int t   = threadIdx.x;

    float acc = 0.f;
    if (mode) {
        const size_t slot = (size_t)row * NBINS + t;
        for (int p = 0; p < NBLOCKS; ++p)
            acc += ws[(size_t)p * PARTIAL_FLOATS + slot];
    } else {
        acc = ws[row * NBINS + t];
    }
    s[t] = acc;
    __syncthreads();

    #pragma unroll
    for (int off = 1; off < NBINS; off <<= 1) {
        float x = (t >= off) ? s[t - off] : 0.f;
        __syncthreads();
        s[t] += x;
        __syncthreads();
    }
    out[row * NBINS + t] = s[t];
}

extern "C" void kernel_launch(void* const* d_in, const int* in_sizes, int n_in,
                              void* d_out, int out_size, void* d_ws, size_t ws_size,
                              hipStream_t stream) {
    const int*   X    = (const int*)d_in[0];
    const float* grad = (const float*)d_in[1];
    const float* hess = (const float*)d_in[2];
    float*       out  = (float*)d_out;
    float*       ws   = (float*)d_ws;
    const int n = in_sizes[1];   // N_SAMPLES

    const int mode = (ws_size >= WS_PARTIAL_BYTES) ? 1 : 0;
    if (!mode)
        hipMemsetAsync(d_ws, 0, 2 * HIST_FLOATS * sizeof(float), stream);

    hipLaunchKernelGGL(_split_hist_kernel, dim3(NBLOCKS), dim3(BLOCK_T), 0, stream,
                       X, grad, hess, ws, n, mode);
    hipLaunchKernelGGL(_split_scan_kernel, dim3(2 * N_FEAT), dim3(NBINS), 0, stream,
                       ws, out, mode);
}